// Round 5
// baseline (164.240 us; speedup 1.0000x reference)
//
#include <hip/hip_runtime.h>
#include <math.h>

// RX gate on qubit 10 of a 22-qubit state, batch=4. Output = REAL PART only
// (fp32, 2^24 elems), verified (absmax 0.0156).
//   o0re = c*r0 + s*i1 ; o1re = c*r1 + s*i0   per batch lane.
//
// Session ledger:
//  R2 (nt loads+stores, ITERS=4, 16MiB k-stride): kernel 41.5 us,
//     FETCH=64 MiB WRITE=64 MiB (3.23 TB/s HBM). Fill kernels: 6.5 TB/s.
//  R3 (plain loads): 61 us, FETCH UNCHANGED -> input L3 residency is set by
//     the harness, not our hints; nt loads = 1.5x throughput via L2 bypass.
//     KEEP nt loads.
//  R4 (ITERS=1, 32768 waves): kernel ~39.5 us (fell below the 40.4 us fill
//     kernels in top-5; e2e 165.7->163.6). Combined traffic 201 MB/39.5us
//     = 5.1 TB/s = 81% of the 6.29 TB/s copy ceiling.
//  R5 (this): 2 pairs/thread, ONE load round trip per wave, all instruction
//     streams fully 64x16B-coalesced (second pair is +1 KiB, NOT +16 MiB:
//     R2's regression was the far stride + 4 serialized round trips).
//     Halves wave count (16384): amortizes launch/sincos/end-of-wave
//     vmcnt-drain 2x. Guards dropped (out covers 2^24 always).
//     Predict: FETCH/WRITE unchanged; kernel 39.5 -> 36-38 us
//     (e2e ~160-162); null => mixed-stream fabric ceiling, prep roofline.

#define QC 2048
#define QB 4
#define JSTRIDE (QC * QB)       // 8192 floats between j=0 and j=1 slices
#define NT     (1 << 21)        // total (a,c) pairs
#define PAIRS_PER_THREAD 2
#define NTHREADS (NT / PAIRS_PER_THREAD)   // 2^20
#define NBLOCKS  (NTHREADS / 256)          // 4096

typedef __attribute__((ext_vector_type(4))) float f32x4;

__global__ __launch_bounds__(256) void rx_gate_kernel(
    const float* __restrict__ theta,
    const float* __restrict__ re,
    const float* __restrict__ im,
    float* __restrict__ out,
    int out_n)
{
    const int tid  = blockIdx.x * blockDim.x + threadIdx.x;  // [0, 2^20)
    const int lane = tid & 63;
    const int wv   = tid >> 6;                               // wave id [0, 16384)

    // Two pairs per thread, 64 apart: every load/store instruction below is
    // 64 lanes x 16B contiguous (1 KiB), pairs p0 and p0+64 are 1 KiB apart.
    const int p0 = wv * 128 + lane;
    const int p1 = p0 + 64;

    // theta is wave-uniform (same address) -> 4 sincos, once
    float c[QB], s[QB];
    {
        const f32x4 th = *reinterpret_cast<const f32x4*>(theta);
        sincosf(0.5f * th.x, &s[0], &c[0]);
        sincosf(0.5f * th.y, &s[1], &c[1]);
        sincosf(0.5f * th.z, &s[2], &c[2]);
        sincosf(0.5f * th.w, &s[3], &c[3]);
    }

    const int a0 = (((p0 >> 11) << 12) | (p0 & 2047)) * QB;  // pair0, j=0
    const int b0 = a0 + JSTRIDE;                             // pair0, j=1
    const int a1 = (((p1 >> 11) << 12) | (p1 & 2047)) * QB;  // pair1, j=0
    const int b1 = a1 + JSTRIDE;                             // pair1, j=1

    // Issue all 8 loads, then one wait (compiler chains vmcnt), compute, store.
    const f32x4 r0a = __builtin_nontemporal_load(reinterpret_cast<const f32x4*>(re + a0));
    const f32x4 i0a = __builtin_nontemporal_load(reinterpret_cast<const f32x4*>(im + a0));
    const f32x4 r1a = __builtin_nontemporal_load(reinterpret_cast<const f32x4*>(re + b0));
    const f32x4 i1a = __builtin_nontemporal_load(reinterpret_cast<const f32x4*>(im + b0));
    const f32x4 r0b = __builtin_nontemporal_load(reinterpret_cast<const f32x4*>(re + a1));
    const f32x4 i0b = __builtin_nontemporal_load(reinterpret_cast<const f32x4*>(im + a1));
    const f32x4 r1b = __builtin_nontemporal_load(reinterpret_cast<const f32x4*>(re + b1));
    const f32x4 i1b = __builtin_nontemporal_load(reinterpret_cast<const f32x4*>(im + b1));

    f32x4 o0a, o1a, o0b, o1b;
    o0a.x = c[0] * r0a.x + s[0] * i1a.x;
    o0a.y = c[1] * r0a.y + s[1] * i1a.y;
    o0a.z = c[2] * r0a.z + s[2] * i1a.z;
    o0a.w = c[3] * r0a.w + s[3] * i1a.w;
    o1a.x = c[0] * r1a.x + s[0] * i0a.x;
    o1a.y = c[1] * r1a.y + s[1] * i0a.y;
    o1a.z = c[2] * r1a.z + s[2] * i0a.z;
    o1a.w = c[3] * r1a.w + s[3] * i0a.w;
    o0b.x = c[0] * r0b.x + s[0] * i1b.x;
    o0b.y = c[1] * r0b.y + s[1] * i1b.y;
    o0b.z = c[2] * r0b.z + s[2] * i1b.z;
    o0b.w = c[3] * r0b.w + s[3] * i1b.w;
    o1b.x = c[0] * r1b.x + s[0] * i0b.x;
    o1b.y = c[1] * r1b.y + s[1] * i0b.y;
    o1b.z = c[2] * r1b.z + s[2] * i0b.z;
    o1b.w = c[3] * r1b.w + s[3] * i0b.w;

    __builtin_nontemporal_store(o0a, reinterpret_cast<f32x4*>(out + a0));
    __builtin_nontemporal_store(o1a, reinterpret_cast<f32x4*>(out + b0));
    __builtin_nontemporal_store(o0b, reinterpret_cast<f32x4*>(out + a1));
    __builtin_nontemporal_store(o1b, reinterpret_cast<f32x4*>(out + b1));
    (void)out_n;
}

extern "C" void kernel_launch(void* const* d_in, const int* in_sizes, int n_in,
                              void* d_out, int out_size, void* d_ws, size_t ws_size,
                              hipStream_t stream) {
    // setup_inputs order: theta[4], state_re[2^24], state_im[2^24], P[4] (fp32)
    const float* theta = (const float*)d_in[0];
    const float* re    = (const float*)d_in[1];
    const float* im    = (const float*)d_in[2];
    float* out = (float*)d_out;

    rx_gate_kernel<<<NBLOCKS, 256, 0, stream>>>(theta, re, im, out, out_size / 4);
}